// Round 3
// baseline (101.266 us; speedup 1.0000x reference)
//
#include <hip/hip_runtime.h>
#include <math.h>

#define NQ 8
#define NDEPTH 3
#define FEAT 512
#define NCLS 10
#define NBATCH 8192

typedef _Float16 v8h __attribute__((ext_vector_type(8)));
typedef _Float16 v4h __attribute__((ext_vector_type(4)));
typedef float v4f __attribute__((ext_vector_type(4)));

// ---------------------------------------------------------------------------
// Workspace layout (re-derived every launch; ws re-poisoned each call):
//   gates: 24*8 f32 @ 0        (768 B)
//   T:     256*10 f32 @ 4096   (10240 B)
//   Bre:   256*256 f16 @ 16384 (131072 B)   packed MFMA-B fragments
//   Bim:   256*256 f16 @ 147456(131072 B)
//   ENC:   8192*256 f16 @ 278528 (4 MiB)
// ---------------------------------------------------------------------------

// ---------------------------------------------------------------------------
// k1: fused RX*RY*RX gate matrices (verified R2 code) + T[i][c] head matrix
// ---------------------------------------------------------------------------
__global__ void precompute(const float* __restrict__ qnn_w,
                           const float* __restrict__ out_w,
                           float* __restrict__ gates, float* __restrict__ T) {
    int i = threadIdx.x;
    if (i < NDEPTH * NQ) {
        float t0 = 0.5f * qnn_w[i * 3 + 0];
        float t1 = 0.5f * qnn_w[i * 3 + 1];
        float t2 = 0.5f * qnn_w[i * 3 + 2];
        float c0 = cosf(t0), s0 = sinf(t0);
        float c1 = cosf(t1), s1 = sinf(t1);
        float c2 = cosf(t2), s2 = sinf(t2);
        float m00r =  c1 * c0, m00i =  s1 * s0;
        float m01r = -s1 * c0, m01i = -c1 * s0;
        float m10r =  s1 * c0, m10i = -c1 * s0;
        float m11r =  c1 * c0, m11i = -s1 * s0;
        float* g = gates + i * 8;
        g[0] =  c2 * m00r + s2 * m10i;  g[1] =  c2 * m00i - s2 * m10r;
        g[2] =  c2 * m01r + s2 * m11i;  g[3] =  c2 * m01i - s2 * m11r;
        g[4] =  s2 * m00i + c2 * m10r;  g[5] = -s2 * m00r + c2 * m10i;
        g[6] =  s2 * m01i + c2 * m11r;  g[7] = -s2 * m01r + c2 * m11i;
    }
    // T[i][c] = sum_q (1 - 2*bit_q(i)) * out_w[c][q]
    if (i < 256) {
#pragma unroll
        for (int c = 0; c < NCLS; c++) {
            float s = 0.f;
#pragma unroll
            for (int q = 0; q < NQ; q++)
                s += (((i >> q) & 1) ? -1.f : 1.f) * out_w[c * NQ + q];
            T[i * NCLS + c] = s;
        }
    }
}

// ---------------------------------------------------------------------------
// DPP helpers (verified R2)
// ---------------------------------------------------------------------------
template <int CTRL, int ROW_MASK>
__device__ __forceinline__ float dpp_term(float v) {
    return __int_as_float(__builtin_amdgcn_update_dpp(
        0, __float_as_int(v), CTRL, ROW_MASK, 0xf, true));
}

__device__ __forceinline__ float wave_sum_bcast(float v) {
    v += dpp_term<0x111, 0xf>(v);
    v += dpp_term<0x112, 0xf>(v);
    v += dpp_term<0x114, 0xf>(v);
    v += dpp_term<0x118, 0xf>(v);
    v += dpp_term<0x142, 0xa>(v);
    v += dpp_term<0x143, 0xc>(v);
    return __int_as_float(__builtin_amdgcn_readlane(__float_as_int(v), 63));
}

__device__ __forceinline__ float bcastlane(float v, int srclane) {
    return __int_as_float(__builtin_amdgcn_readlane(__float_as_int(v), srclane));
}

template <int CTRL>
__device__ __forceinline__ float dpp_xor(float v) {
    return __int_as_float(__builtin_amdgcn_update_dpp(
        0, __float_as_int(v), CTRL, 0xf, 0xf, true));
}

__device__ __forceinline__ float fast_tanh(float v) {
    float e = __expf(2.f * v);
    return 1.f - 2.f / (e + 1.f);
}

// ---------------------------------------------------------------------------
// Gate application helpers (verified R2). State: amp index = lane*4 + j.
// ---------------------------------------------------------------------------
__device__ __forceinline__ void cgate_pair(const float* __restrict__ u,
        float& r0, float& i0, float& r1, float& i1) {
    float nr0 = u[0]*r0 - u[1]*i0 + u[2]*r1 - u[3]*i1;
    float ni0 = u[0]*i0 + u[1]*r0 + u[2]*i1 + u[3]*r1;
    float nr1 = u[4]*r0 - u[5]*i0 + u[6]*r1 - u[7]*i1;
    float ni1 = u[4]*i0 + u[5]*r0 + u[6]*i1 + u[7]*r1;
    r0 = nr0; i0 = ni0; r1 = nr1; i1 = ni1;
}

__device__ __forceinline__ void cgate_shfl(const float* __restrict__ u, int bit,
        int mask, float (&re)[4], float (&im)[4]) {
    float dr  = bit ? u[6] : u[0], di = bit ? u[7] : u[1];
    float orr = bit ? u[4] : u[2], oi = bit ? u[5] : u[3];
#pragma unroll
    for (int j = 0; j < 4; j++) {
        float pr = __shfl_xor(re[j], mask);
        float pi = __shfl_xor(im[j], mask);
        float nr = dr*re[j] - di*im[j] + orr*pr - oi*pi;
        float ni = dr*im[j] + di*re[j] + orr*pi + oi*pr;
        re[j] = nr; im[j] = ni;
    }
}

template <int CTRL>
__device__ __forceinline__ void cgate_dpp(const float* __restrict__ u, int bit,
        float (&re)[4], float (&im)[4]) {
    float dr  = bit ? u[6] : u[0], di = bit ? u[7] : u[1];
    float orr = bit ? u[4] : u[2], oi = bit ? u[5] : u[3];
#pragma unroll
    for (int j = 0; j < 4; j++) {
        float pr = dpp_xor<CTRL>(re[j]);
        float pi = dpp_xor<CTRL>(im[j]);
        float nr = dr*re[j] - di*im[j] + orr*pr - oi*pi;
        float ni = dr*im[j] + di*re[j] + orr*pi + oi*pr;
        re[j] = nr; im[j] = ni;
    }
}

// Applies the full variational circuit to (re, im) — verbatim verified R2 loop
__device__ __forceinline__ void apply_circuit(const float* __restrict__ gates,
        int lane, float (&re)[4], float (&im)[4]) {
#pragma unroll
    for (int l = 0; l < NDEPTH; l++) {
        const float* g = gates + l * NQ * 8;
        cgate_pair(g, re[0], im[0], re[1], im[1]);
        cgate_pair(g, re[2], im[2], re[3], im[3]);
        cgate_pair(g + 8,  re[0], im[0], re[2], im[2]);
        cgate_pair(g + 8,  re[1], im[1], re[3], im[3]);
        cgate_dpp<0xB1>(g + 16, lane & 1,        re, im);
        cgate_dpp<0x4E>(g + 24, (lane >> 1) & 1, re, im);
        cgate_shfl(g + 32, (lane >> 2) & 1, 4,  re, im);
        cgate_shfl(g + 40, (lane >> 3) & 1, 8,  re, im);
        cgate_shfl(g + 48, (lane >> 4) & 1, 16, re, im);
        cgate_shfl(g + 56, (lane >> 5) & 1, 32, re, im);
        // CNOT ladder (verified R2)
        { float t = re[1]; re[1] = re[3]; re[3] = t;
          t = im[1]; im[1] = im[3]; im[3] = t; }
        int base  = lane ^ ((lane << 1) & 63);
        int base2 = base ^ 1;
        re[0] = __shfl(re[0], base);  im[0] = __shfl(im[0], base);
        re[1] = __shfl(re[1], base);  im[1] = __shfl(im[1], base);
        re[2] = __shfl(re[2], base2); im[2] = __shfl(im[2], base2);
        re[3] = __shfl(re[3], base2); im[3] = __shfl(im[3], base2);
        int bit5 = (lane >> 5) & 1;
        {
            float t0 = bit5 ? re[1] : re[0], t1 = bit5 ? re[0] : re[1];
            float t2 = bit5 ? re[3] : re[2], t3 = bit5 ? re[2] : re[3];
            re[0] = t0; re[1] = t1; re[2] = t2; re[3] = t3;
            t0 = bit5 ? im[1] : im[0]; t1 = bit5 ? im[0] : im[1];
            t2 = bit5 ? im[3] : im[2]; t3 = bit5 ? im[2] : im[3];
            im[0] = t0; im[1] = t1; im[2] = t2; im[3] = t3;
        }
    }
}

// ---------------------------------------------------------------------------
// k2: encoding product states -> ENC (8192 x 256, f16). Reuses verified R2
// encoding front-end; enc is real and separable so no gate application.
// ---------------------------------------------------------------------------
__global__ __launch_bounds__(256) void enc_kernel(
        const float* __restrict__ x, const float* __restrict__ proj_w,
        _Float16* __restrict__ enc) {
    int tid  = threadIdx.x;
    int lane = tid & 63;
    int b    = blockIdx.x * 4 + (tid >> 6);

    const float4* xr4 = (const float4*)(x + (size_t)b * FEAT);
    float4 xa = xr4[lane], xb = xr4[lane + 64];
    float dq[8];
#pragma unroll
    for (int q = 0; q < 8; q++) {
        const float4* pw4 = (const float4*)(proj_w + q * FEAT);
        float4 wa = pw4[lane], wb = pw4[lane + 64];
        float acc = xa.x*wa.x + xa.y*wa.y + xa.z*wa.z + xa.w*wa.w
                  + xb.x*wb.x + xb.y*wb.y + xb.z*wb.z + xb.w*wb.w;
        dq[q] = wave_sum_bcast(acc);
    }
    int qsel = lane >> 3;
    float a0 = (qsel & 4) ? dq[4] : dq[0];
    float a1 = (qsel & 4) ? dq[5] : dq[1];
    float a2 = (qsel & 4) ? dq[6] : dq[2];
    float a3 = (qsel & 4) ? dq[7] : dq[3];
    float b0 = (qsel & 2) ? a2 : a0;
    float b1 = (qsel & 2) ? a3 : a1;
    float dsel = (qsel & 1) ? b1 : b0;
    float th = fast_tanh(dsel) * 0.78539816339744830962f;
    float se = __sinf(th), ce = __cosf(th);
    float cq[8], sq[8];
#pragma unroll
    for (int q = 0; q < 8; q++) {
        cq[q] = bcastlane(ce, q * 8);
        sq[q] = bcastlane(se, q * 8);
    }
    float F = 1.f;
#pragma unroll
    for (int q = 2; q < 8; q++) {
        int bit = (lane >> (q - 2)) & 1;
        F *= bit ? sq[q] : cq[q];
    }
    v4h ev;
    ev[0] = (_Float16)(F * cq[0] * cq[1]);
    ev[1] = (_Float16)(F * sq[0] * cq[1]);
    ev[2] = (_Float16)(F * cq[0] * sq[1]);
    ev[3] = (_Float16)(F * sq[0] * sq[1]);
    *(v4h*)(enc + (size_t)b * 256 + lane * 4) = ev;
}

// ---------------------------------------------------------------------------
// k3: build the circuit unitary U by simulating the 256 basis states (wave p
// computes column p = U e_p using the verified circuit code), then scatter
// into MFMA-B fragment-packed layout:
//   flat(k, n) = ((t*8 + kk)*64 + lane')*8 + j
//   t = n>>4, kk = k>>5, lane' = ((k>>3)&3)*16 + (n&15), j = k&7
// where B[k=p][n=i] = U[i][p].
// ---------------------------------------------------------------------------
__global__ __launch_bounds__(256) void build_w(
        const float* __restrict__ gates,
        _Float16* __restrict__ Bre, _Float16* __restrict__ Bim) {
    int tid  = threadIdx.x;
    int lane = tid & 63;
    int p    = blockIdx.x * 4 + (tid >> 6); // basis state index 0..255

    float re[4], im[4];
#pragma unroll
    for (int j = 0; j < 4; j++) {
        re[j] = (lane * 4 + j == p) ? 1.f : 0.f;
        im[j] = 0.f;
    }
    apply_circuit(gates, lane, re, im);

    int t  = lane >> 2;           // n>>4 for n = lane*4+r
    int kk = p >> 5;
    int qp = (p >> 3) & 3;
    int j  = p & 7;
#pragma unroll
    for (int r = 0; r < 4; r++) {
        int n15  = (lane & 3) * 4 + r;
        int flat = ((t * 8 + kk) * 64 + qp * 16 + n15) * 8 + j;
        Bre[flat] = (_Float16)re[r];
        Bim[flat] = (_Float16)im[r];
    }
}

// ---------------------------------------------------------------------------
// k4: PSI = ENC x B (re & im), fused |psi|^2 * T epilogue + head.
// One wave per 16 batch rows; full 256 columns; K = 256.
// A-frag: A[m=lane&15][k=quad*8+j]; B-frag: B[k=quad*8+j][n=lane&15];
// C/D: col=lane&15, row=quad*4+reg  [verified m89].
// ---------------------------------------------------------------------------
__global__ __launch_bounds__(64) void gemm_head(
        const _Float16* __restrict__ enc,
        const _Float16* __restrict__ Bre, const _Float16* __restrict__ Bim,
        const float* __restrict__ T, const float* __restrict__ out_b,
        float* __restrict__ out) {
    int lane = threadIdx.x;
    int rowbase = blockIdx.x * 16;
    int m = lane & 15, quad = lane >> 4;

    v8h a[8];
#pragma unroll
    for (int kk = 0; kk < 8; kk++)
        a[kk] = *(const v8h*)(enc + (size_t)(rowbase + m) * 256 + kk * 32 + quad * 8);

    float oacc[4][NCLS] = {};
#pragma unroll
    for (int t = 0; t < 16; t++) {
        int col = t * 16 + m;
        float tc[NCLS];
#pragma unroll
        for (int c = 0; c < NCLS; c++) tc[c] = T[col * NCLS + c];

        v4f ar = {0.f, 0.f, 0.f, 0.f}, ai = {0.f, 0.f, 0.f, 0.f};
#pragma unroll
        for (int kk = 0; kk < 8; kk++) {
            size_t fb = ((size_t)(t * 8 + kk)) * 512 + (size_t)lane * 8;
            v8h br = *(const v8h*)(Bre + fb);
            v8h bi = *(const v8h*)(Bim + fb);
            ar = __builtin_amdgcn_mfma_f32_16x16x32_f16(a[kk], br, ar, 0, 0, 0);
            ai = __builtin_amdgcn_mfma_f32_16x16x32_f16(a[kk], bi, ai, 0, 0, 0);
        }
#pragma unroll
        for (int r = 0; r < 4; r++) {
            float pv = ar[r] * ar[r] + ai[r] * ai[r];
#pragma unroll
            for (int c = 0; c < NCLS; c++)
                oacc[r][c] = fmaf(pv, tc[c], oacc[r][c]);
        }
    }
    // reduce over the 16 lanes of each quad-group (cols) via DPP row_shr
#pragma unroll
    for (int r = 0; r < 4; r++) {
#pragma unroll
        for (int c = 0; c < NCLS; c++) {
            float v = oacc[r][c];
            v += dpp_term<0x111, 0xf>(v);
            v += dpp_term<0x112, 0xf>(v);
            v += dpp_term<0x114, 0xf>(v);
            v += dpp_term<0x118, 0xf>(v);
            oacc[r][c] = v; // lane 15 of each row-group holds the sum
        }
    }
    if (m == 15) {
#pragma unroll
        for (int r = 0; r < 4; r++) {
            int row = rowbase + quad * 4 + r;
#pragma unroll
            for (int c = 0; c < NCLS; c++)
                out[row * NCLS + c] = oacc[r][c] + out_b[c];
        }
    }
}

extern "C" void kernel_launch(void* const* d_in, const int* in_sizes, int n_in,
                              void* d_out, int out_size, void* d_ws, size_t ws_size,
                              hipStream_t stream) {
    const float* x      = (const float*)d_in[0];
    const float* proj_w = (const float*)d_in[1];
    const float* qnn_w  = (const float*)d_in[2];
    const float* out_w  = (const float*)d_in[3];
    const float* out_b  = (const float*)d_in[4];
    float* out = (float*)d_out;

    char* ws = (char*)d_ws;
    float*     gates = (float*)(ws + 0);
    float*     T     = (float*)(ws + 4096);
    _Float16*  Bre   = (_Float16*)(ws + 16384);
    _Float16*  Bim   = (_Float16*)(ws + 16384 + 131072);
    _Float16*  enc   = (_Float16*)(ws + 278528);

    precompute<<<1, 256, 0, stream>>>(qnn_w, out_w, gates, T);
    enc_kernel<<<NBATCH / 4, 256, 0, stream>>>(x, proj_w, enc);
    build_w<<<64, 256, 0, stream>>>(gates, Bre, Bim);
    gemm_head<<<NBATCH / 16, 64, 0, stream>>>(enc, Bre, Bim, T, out_b, out);
}